// Round 4
// baseline (766.264 us; speedup 1.0000x reference)
//
#include <hip/hip_runtime.h>
#include <hip/hip_bf16.h>

#define Sd 442368      // D*H*W
#define HWc 9216
#define Wc 96
#define Hc 96
#define Dc 48

typedef unsigned short u16;
typedef unsigned int u32;
typedef __attribute__((ext_vector_type(8))) short short8;
typedef __attribute__((ext_vector_type(4))) float f32x4;
typedef __attribute__((ext_vector_type(2))) float f32x2;

static __device__ __forceinline__ u16 f2bf(float f){
    __hip_bfloat16 h = __float2bfloat16(f);
    return *reinterpret_cast<u16*>(&h);
}
static __device__ __forceinline__ u32 pk2(float a, float b){
    return ((u32)f2bf(b) << 16) | (u32)f2bf(a);
}
static __device__ __forceinline__ float bflo(u32 u){ return __uint_as_float(u << 16); }
static __device__ __forceinline__ float bfhi(u32 u){ return __uint_as_float(u & 0xffff0000u); }
static __device__ __forceinline__ f32x2 unp2(u32 u){
    f32x2 r; r.x = __uint_as_float(u << 16); r.y = __uint_as_float(u & 0xffff0000u); return r;
}

static __device__ __forceinline__ short8 ldfrag_w(const float* p){
    float4 f0 = *reinterpret_cast<const float4*>(p);
    float4 f1 = *reinterpret_cast<const float4*>(p + 4);
    union { short8 s; u32 u[4]; } r;
    r.u[0] = pk2(f0.x, f0.y); r.u[1] = pk2(f0.z, f0.w);
    r.u[2] = pk2(f1.x, f1.y); r.u[3] = pk2(f1.z, f1.w);
    return r.s;
}

// ---------------- Pass A: K,V projection via MFMA, bf16 [vox][128] ----------------
#define NBLK_A 3456
__global__ __launch_bounds__(256, 2) void kv_mfma(
    const float* __restrict__ x, const float* __restrict__ qkv_w,
    const float* __restrict__ qkv_b, u16* __restrict__ KV)
{
    int bid = blockIdx.x;
    bid = (bid & 7) * (NBLK_A / 8) + (bid >> 3);
    int batch = bid / (NBLK_A / 2);
    int s0 = (bid - batch * (NBLK_A / 2)) * 256;
    int t = threadIdx.x, lane = t & 63, wv = t >> 6;
    int lo = lane & 15, hi = lane >> 4;
    __shared__ u16 L[256 * 72];

    const float* xb = x + (size_t)batch * 64 * Sd + s0;
    {
        u32 pk[32];
#pragma unroll
        for (int c = 0; c < 64; c += 2){
            float f0 = xb[(size_t)c * Sd + t];
            float f1 = xb[(size_t)(c + 1) * Sd + t];
            pk[c >> 1] = pk2(f0, f1);
        }
#pragma unroll
        for (int k = 0; k < 8; ++k){
            uint4 u; u.x = pk[k*4+0]; u.y = pk[k*4+1]; u.z = pk[k*4+2]; u.w = pk[k*4+3];
            *reinterpret_cast<uint4*>(&L[t * 72 + k * 8]) = u;
        }
    }
    // staging is wave-local (thread t writes row t; wave reads rows [wv*64, wv*64+64))
    // same-wave DS ops are in-order -> no barrier needed

    short8 af[8][2];
    f32x4  bias[8];
#pragma unroll
    for (int mt = 0; mt < 8; ++mt){
#pragma unroll
        for (int kh = 0; kh < 2; ++kh)
            af[mt][kh] = ldfrag_w(qkv_w + (size_t)(64 + mt*16 + lo) * 64 + kh*32 + hi*8);
        bias[mt] = *reinterpret_cast<const f32x4*>(qkv_b + 64 + mt*16 + hi*4);
    }

#pragma unroll
    for (int nt = 0; nt < 4; ++nt){
        int vl = wv * 64 + nt * 16 + lo;
        const u16* br = &L[vl * 72 + hi * 8];
        short8 b0 = *reinterpret_cast<const short8*>(br);
        short8 b1 = *reinterpret_cast<const short8*>(br + 32);
        u16* kvrow = KV + (size_t)(batch * Sd + s0 + vl) * 128 + hi * 4;
#pragma unroll
        for (int mt = 0; mt < 8; ++mt){
            f32x4 acc = bias[mt];
            acc = __builtin_amdgcn_mfma_f32_16x16x32_bf16(af[mt][0], b0, acc, 0, 0, 0);
            acc = __builtin_amdgcn_mfma_f32_16x16x32_bf16(af[mt][1], b1, acc, 0, 0, 0);
            uint2 st; st.x = pk2(acc[0], acc[1]); st.y = pk2(acc[2], acc[3]);
            *reinterpret_cast<uint2*>(kvrow + mt * 16) = st;
        }
    }
}

// ---------------- Pass B: fused online-softmax attention, 2 threads/voxel ----------------
#define NBLK_B 6912
#define SCLOG 0.18033688011112042f   // 0.125 * log2(e)

__global__ __launch_bounds__(256, 4) void attn_fused(
    const float* __restrict__ x, const float* __restrict__ qkv_w,
    const float* __restrict__ qkv_b, const float* __restrict__ out_w,
    const float* __restrict__ out_b, const float* __restrict__ rel_pos,
    const u16* __restrict__ KV, float* __restrict__ out)
{
    int bid = blockIdx.x;
    bid = (bid & 7) * (NBLK_B / 8) + (bid >> 3);
    int batch = bid / (NBLK_B / 2);
    int s0 = (bid - batch * (NBLK_B / 2)) * 128;
    int t = threadIdx.x, lane = t & 63, wv = t >> 6;
    int lo = lane & 15, hi = lane >> 4;
    int vt = t >> 1, half = t & 1;

    __shared__ u16  Lx[128 * 72];    // x bf16 -> Q bf16 (in place) -> attn-out bf16
    __shared__ float Lr[128 * 27];   // rel-logits fp32, pre-scaled by SCLOG

    const float* xb = x + (size_t)batch * 64 * Sd + s0;
    {   // stage own 32 channels of voxel vt (wave-local rows)
        u32 pk[16];
#pragma unroll
        for (int c2 = 0; c2 < 32; c2 += 2){
            float f0 = xb[(size_t)(half*32 + c2) * Sd + vt];
            float f1 = xb[(size_t)(half*32 + c2 + 1) * Sd + vt];
            pk[c2 >> 1] = pk2(f0, f1);
        }
#pragma unroll
        for (int k = 0; k < 4; ++k){
            uint4 u; u.x = pk[k*4+0]; u.y = pk[k*4+1]; u.z = pk[k*4+2]; u.w = pk[k*4+3];
            *reinterpret_cast<uint4*>(&Lx[vt * 72 + half * 32 + k * 8]) = u;
        }
    }

    {   // Q-projection MFMA; overwrite own wave's rows of Lx with Q bf16
        short8 qa[4][2];
        f32x4  qbias[4];
#pragma unroll
        for (int mt = 0; mt < 4; ++mt){
#pragma unroll
            for (int kh = 0; kh < 2; ++kh)
                qa[mt][kh] = ldfrag_w(qkv_w + (size_t)(mt*16 + lo) * 64 + kh*32 + hi*8);
            qbias[mt] = *reinterpret_cast<const f32x4*>(qkv_b + mt*16 + hi*4);
        }
#pragma unroll
        for (int nt = 0; nt < 2; ++nt){
            int vl = wv * 32 + nt * 16 + lo;
            const u16* br = &Lx[vl * 72 + hi * 8];
            short8 b0 = *reinterpret_cast<const short8*>(br);
            short8 b1 = *reinterpret_cast<const short8*>(br + 32);
#pragma unroll
            for (int mt = 0; mt < 4; ++mt){
                f32x4 acc = qbias[mt];
                acc = __builtin_amdgcn_mfma_f32_16x16x32_bf16(qa[mt][0], b0, acc, 0, 0, 0);
                acc = __builtin_amdgcn_mfma_f32_16x16x32_bf16(qa[mt][1], b1, acc, 0, 0, 0);
                uint2 st; st.x = pk2(acc[0], acc[1]); st.y = pk2(acc[2], acc[3]);
                *reinterpret_cast<uint2*>(&Lx[vl * 72 + mt * 16 + hi * 4]) = st;
            }
        }
    }

    {   // rel-logits MFMA: R(27x64 pad 32) x Q -> Lr fp32 (scaled by SCLOG)
        short8 ra[2][2];
#pragma unroll
        for (int mt = 0; mt < 2; ++mt){
            int o = mt * 16 + lo;
#pragma unroll
            for (int kh = 0; kh < 2; ++kh){
                float f[8];
#pragma unroll
                for (int j = 0; j < 8; ++j){
                    int k = kh * 32 + hi * 8 + j;
                    f[j] = (o < 27) ? rel_pos[k * 27 + o] : 0.f;
                }
                union { short8 s; u32 u[4]; } r;
                r.u[0] = pk2(f[0], f[1]); r.u[1] = pk2(f[2], f[3]);
                r.u[2] = pk2(f[4], f[5]); r.u[3] = pk2(f[6], f[7]);
                ra[mt][kh] = r.s;
            }
        }
#pragma unroll
        for (int nt = 0; nt < 2; ++nt){
            int vl = wv * 32 + nt * 16 + lo;
            const u16* br = &Lx[vl * 72 + hi * 8];
            short8 b0 = *reinterpret_cast<const short8*>(br);
            short8 b1 = *reinterpret_cast<const short8*>(br + 32);
            f32x4 a0 = {0.f, 0.f, 0.f, 0.f};
            f32x4 a1 = {0.f, 0.f, 0.f, 0.f};
            a0 = __builtin_amdgcn_mfma_f32_16x16x32_bf16(ra[0][0], b0, a0, 0, 0, 0);
            a0 = __builtin_amdgcn_mfma_f32_16x16x32_bf16(ra[0][1], b1, a0, 0, 0, 0);
            a1 = __builtin_amdgcn_mfma_f32_16x16x32_bf16(ra[1][0], b0, a1, 0, 0, 0);
            a1 = __builtin_amdgcn_mfma_f32_16x16x32_bf16(ra[1][1], b1, a1, 0, 0, 0);
#pragma unroll
            for (int j = 0; j < 4; ++j)
                Lr[vl * 27 + hi * 4 + j] = a0[j] * SCLOG;
#pragma unroll
            for (int j = 0; j < 4; ++j){
                int row = 16 + hi * 4 + j;
                if (row < 27) Lr[vl * 27 + row] = a1[j] * SCLOG;
            }
        }
    }

    // per-thread: own half of Q, pre-scaled, as f32x2 pairs
    f32x2 q2[16];
#pragma unroll
    for (int k = 0; k < 4; ++k){
        uint4 q4 = *reinterpret_cast<const uint4*>(&Lx[vt * 72 + half * 32 + k * 8]);
        q2[k*4+0] = unp2(q4.x) * SCLOG;
        q2[k*4+1] = unp2(q4.y) * SCLOG;
        q2[k*4+2] = unp2(q4.z) * SCLOG;
        q2[k*4+3] = unp2(q4.w) * SCLOG;
    }

    int s = s0 + vt;
    int d = s / HWc; int r = s - d * HWc; int h3 = r / Wc; int w3 = r - h3 * Wc;

    // clamped per-axis voxel offsets + validity
    int cdm = (d  > 0)      ? -HWc : 0;
    int cdp = (d  < Dc - 1) ?  HWc : 0;
    int chm = (h3 > 0)      ? -Wc  : 0;
    int chp = (h3 < Hc - 1) ?  Wc  : 0;
    int cwm = (w3 > 0)      ? -1   : 0;
    int cwp = (w3 < Wc - 1) ?  1   : 0;
    bool vdm = d  > 0, vdp = d  < Dc - 1;
    bool vhm = h3 > 0, vhp = h3 < Hc - 1;
    bool vwm = w3 > 0, vwp = w3 < Wc - 1;

    const char* KVc = reinterpret_cast<const char*>(KV);
    int kbase = (batch * Sd + s) * 256 + half * 64;
    const float* lr = &Lr[vt * 27];

    float m = -1e30f, l = 0.f;
    f32x2 acc[16];
#pragma unroll
    for (int i = 0; i < 16; ++i) acc[i] = (f32x2){0.f, 0.f};

#pragma unroll
    for (int o = 0; o < 27; ++o){
        const int di = o / 9 - 1, dj = (o / 3) % 3 - 1, dk = o % 3 - 1;
        int doff = (di < 0 ? cdm : di > 0 ? cdp : 0)
                 + (dj < 0 ? chm : dj > 0 ? chp : 0)
                 + (dk < 0 ? cwm : dk > 0 ? cwp : 0);
        bool valid = (di < 0 ? vdm : di > 0 ? vdp : true)
                  && (dj < 0 ? vhm : dj > 0 ? vhp : true)
                  && (dk < 0 ? vwm : dk > 0 ? vwp : true);
        const uint4* p4 = reinterpret_cast<const uint4*>(KVc + (kbase + doff * 256));

        uint4 kk[4];
#pragma unroll
        for (int k = 0; k < 4; ++k) kk[k] = p4[k];
        uint4 vv[4];
#pragma unroll
        for (int k = 0; k < 4; ++k) vv[k] = p4[8 + k];

        f32x2 dd = {0.f, 0.f};
#pragma unroll
        for (int k = 0; k < 4; ++k){
            dd += unp2(kk[k].x) * q2[k*4+0];
            dd += unp2(kk[k].y) * q2[k*4+1];
            dd += unp2(kk[k].z) * q2[k*4+2];
            dd += unp2(kk[k].w) * q2[k*4+3];
        }
        float dot = dd.x + dd.y;
        dot += __shfl_xor(dot, 1);
        dot = valid ? dot : 0.f;
        float lgm = dot + lr[o];

        float mn = fmaxf(m, lgm);
        if (__any(mn > m + 8.f)){
            float sc = __builtin_amdgcn_exp2f(m - mn);
            l *= sc;
            f32x2 sc2 = {sc, sc};
#pragma unroll
            for (int i = 0; i < 16; ++i) acc[i] *= sc2;
            m = mn;
        }
        float p = __builtin_amdgcn_exp2f(lgm - m);
        l += p;
        float pv = valid ? p : 0.f;
        f32x2 p2 = {pv, pv};
#pragma unroll
        for (int k = 0; k < 4; ++k){
            acc[k*4+0] += unp2(vv[k].x) * p2;
            acc[k*4+1] += unp2(vv[k].y) * p2;
            acc[k*4+2] += unp2(vv[k].z) * p2;
            acc[k*4+3] += unp2(vv[k].w) * p2;
        }
    }

    {   // normalize + residual (fp32 re-read of x)
        float inv = 1.f / l;
        f32x2 inv2 = {inv, inv};
        const float* xv = x + ((size_t)batch * 64 + half * 32) * Sd + (s0 + vt);
#pragma unroll
        for (int i = 0; i < 16; ++i){
            acc[i] *= inv2;
            acc[i].x += xv[(size_t)(2*i)     * Sd];
            acc[i].y += xv[(size_t)(2*i + 1) * Sd];
        }
        // write attn-out (own half) bf16 into Lx (own wave's rows)
#pragma unroll
        for (int k = 0; k < 4; ++k){
            uint4 u;
            u.x = pk2(acc[k*4+0].x, acc[k*4+0].y);
            u.y = pk2(acc[k*4+1].x, acc[k*4+1].y);
            u.z = pk2(acc[k*4+2].x, acc[k*4+2].y);
            u.w = pk2(acc[k*4+3].x, acc[k*4+3].y);
            *reinterpret_cast<uint4*>(&Lx[vt * 72 + half * 32 + k * 8]) = u;
        }
    }

    {   // out-projection MFMA -> fp32 stores
        short8 oa[4][2];
        f32x4  obias[4];
#pragma unroll
        for (int mt = 0; mt < 4; ++mt){
#pragma unroll
            for (int kh = 0; kh < 2; ++kh)
                oa[mt][kh] = ldfrag_w(out_w + (size_t)(mt*16 + lo) * 64 + kh*32 + hi*8);
            obias[mt] = *reinterpret_cast<const f32x4*>(out_b + mt*16 + hi*4);
        }
#pragma unroll
        for (int nt = 0; nt < 2; ++nt){
            int vl = wv * 32 + nt * 16 + lo;
            const u16* br = &Lx[vl * 72 + hi * 8];
            short8 b0 = *reinterpret_cast<const short8*>(br);
            short8 b1 = *reinterpret_cast<const short8*>(br + 32);
#pragma unroll
            for (int mt = 0; mt < 4; ++mt){
                f32x4 a4 = obias[mt];
                a4 = __builtin_amdgcn_mfma_f32_16x16x32_bf16(oa[mt][0], b0, a4, 0, 0, 0);
                a4 = __builtin_amdgcn_mfma_f32_16x16x32_bf16(oa[mt][1], b1, a4, 0, 0, 0);
                float* op = out + ((size_t)batch * 64 + mt*16 + hi*4) * Sd + (s0 + vl);
                op[0]              = a4[0];
                op[(size_t)Sd]     = a4[1];
                op[(size_t)2*Sd]   = a4[2];
                op[(size_t)3*Sd]   = a4[3];
            }
        }
    }
}

extern "C" void kernel_launch(void* const* d_in, const int* in_sizes, int n_in,
                              void* d_out, int out_size, void* d_ws, size_t ws_size,
                              hipStream_t stream) {
    const float* x       = (const float*)d_in[0];
    const float* qkv_w   = (const float*)d_in[1];
    const float* qkv_b   = (const float*)d_in[2];
    const float* out_w   = (const float*)d_in[3];
    const float* out_b   = (const float*)d_in[4];
    const float* rel_pos = (const float*)d_in[5];
    float* out = (float*)d_out;
    u16* KV = (u16*)d_ws;   // 884736 * 128 * 2B = 216 MB

    kv_mfma<<<NBLK_A, 256, 0, stream>>>(x, qkv_w, qkv_b, KV);
    attn_fused<<<NBLK_B, 256, 0, stream>>>(x, qkv_w, qkv_b, out_w, out_b,
                                           rel_pos, KV, out);
}